// Round 18
// baseline (23.558 us; speedup 1.0000x reference)
//
#include <hip/hip_runtime.h>
#include <math.h>

// BipolarMorphological2D SMorph as a bf16 MFMA GEMM (R18).
// delta-form: e^kf = 1 + delta -> d = S_m + GEMM(m,delta); n = S_mlm + GEMM(..)
//   M = 7200 (s*2+sign), N = 256 (o*4+tbl), K = 576 (c*2+{m,mlm} per 3x3 pos)
// R18 vs R17: gemm wave-split doubled again (R15's proven lever): 8 waves
// (kq2 x nsub4), wave = 32M x 32N x 9 steps -> 2 A + 2 B loads + 4 MFMA/step,
// acc 16 VGPR (max lookahead), 3600 waves = 3.5/SIMD, 2 blocks/CU.
// Prep unchanged (unique pixm table + frag-packed B).

typedef float  f32x4 __attribute__((ext_vector_type(4)));
typedef short  s16x8 __attribute__((ext_vector_type(8)));

#define BB   4
#define CC   32
#define HH   32
#define WW   32
#define OO   64
#define HO   30
#define WO   30
#define NSP  900
#define KDIM 576

#define T1   131072            // branch1: pixel sums + pixm pack
#define TB   18432             // branch2: B pack

__device__ __forceinline__ unsigned short f2bf(float f) {
    unsigned u = __float_as_uint(f);
    return (unsigned short)((u + 0x7FFFu + ((u >> 16) & 1u)) >> 16);
}

// ---- prep: pixs[pix] = fp32 c-sums (Smp, Smlmp, Smn, Smlmn)
//            pixm[pix*64 + sign*32 + c] = packed bf16 (m | mlm<<16)
//            bt: bf16 B in MFMA-frag order: [ng(16)][step(18)][lane(64)] x 16B
__global__ __launch_bounds__(256) void smorph_prep(
    const float* __restrict__ x, const float* __restrict__ k1,
    const float* __restrict__ k2, float4* __restrict__ pixs,
    unsigned* __restrict__ pixm, unsigned short* __restrict__ bt)
{
    const int t = blockIdx.x * 256 + threadIdx.x;

    if (t < T1) {
        const int pix = t >> 5, c = t & 31;
        const int b = pix >> 10, h = (pix >> 5) & 31, w = pix & 31;
        float v = x[b*32768 + c*1024 + h*32 + w];
        float mp = fmaxf(v, 0.1f), mn = fmaxf(-v, 0.1f);
        float lp = mp * logf(mp), ln_ = mn * logf(mn);
        pixm[pix*64      + c] = (unsigned)f2bf(mp) | ((unsigned)f2bf(lp)  << 16);
        pixm[pix*64 + 32 + c] = (unsigned)f2bf(mn) | ((unsigned)f2bf(ln_) << 16);
        float s0 = mp, s1 = lp, s2 = mn, s3 = ln_;
#pragma unroll
        for (int m = 16; m >= 1; m >>= 1) {
            s0 += __shfl_xor(s0, m); s1 += __shfl_xor(s1, m);
            s2 += __shfl_xor(s2, m); s3 += __shfl_xor(s3, m);
        }
        if (c == 0) pixs[pix] = make_float4(s0, s1, s2, s3);
    } else if (t < T1 + TB) {
        const int u3 = t - T1;
        const int o = u3 & 63, p = u3 >> 6;
        const float a = k1[u3], b2 = k2[u3];
        const float d1 = expm1f(a),  q1 = a  * expf(a);
        const float d2 = expm1f(b2), q2 = b2 * expf(b2);
        const float vals[4][2] = {{d1, 0.f}, {q1, d1}, {d2, 0.f}, {q2, d2}};
#pragma unroll
        for (int tbl = 0; tbl < 4; ++tbl) {
            const int n = o*4 + tbl;
#pragma unroll
            for (int ks = 0; ks < 2; ++ks) {
                const int k    = 2*p + ks;
                const int st   = k >> 5, k32 = k & 31;
                const int lane = (n & 15) + ((k32 >> 3) << 4);
                bt[((n >> 4)*18 + st)*512 + lane*8 + (k32 & 7)] = f2bf(vals[tbl][ks]);
            }
        }
    }
}

// ---- GEMM: 450 blocks (225 bm x 2 nh) x 512 thr (8 waves: kq2 x nsub4).
// Wave: 32M x 32N x 9 steps (2 A-loads, 2 B-loads, 4 MFMA per step).
__global__ __launch_bounds__(512, 2) void smorph_gemm(
    const unsigned* __restrict__ pixm, const unsigned short* __restrict__ bt,
    const float4* __restrict__ pixs, const float* __restrict__ bias,
    float* __restrict__ out)
{
    __shared__ float cmb[4][1024];               // 16 KB: K-combine (per nsub)
    __shared__ __align__(16) float epi[4][32*34];// 17.4 KB: epilogue (per nsub)

    const int tid  = threadIdx.x;
    const int l    = tid & 63;
    const int w    = tid >> 6;                 // wave 0..7
    const int kq   = w >> 2;                   // K-half (step parity)
    const int nsub = w & 3;                    // 32-col N-slab within nh
    const int bm   = blockIdx.x >> 1;          // M-tile (16 s, 32 rows)
    const int nh   = blockIdx.x & 1;
    const int N0   = nh*128 + nsub*32;
    const int ng0  = N0 >> 4;                  // two 16-col groups: ng0, ng0+1

    const int lr = l & 15;
    const int lg = l >> 4;

    // ---- per-lane fp32 window sums (epilogue only)
    float4 S;
    {
        const int s  = bm*16 + lr;
        const int b  = s / NSP, r = s - b*NSP;
        const int ho = r / WO,  wo = r - WO*(r/WO);
        const float4* P = pixs + (b*1024 + ho*32 + wo);
        float4 a = make_float4(0,0,0,0);
#pragma unroll
        for (int kh = 0; kh < 3; ++kh)
#pragma unroll
            for (int kw = 0; kw < 3; ++kw) {
                float4 v = P[kh*32 + kw];
                a.x += v.x; a.y += v.y; a.z += v.z; a.w += v.w;
            }
        S = a;
    }

    // A lane byte-offsets into pixm: pix*256 + sign*128 + lg*16
    unsigned offA[2];
    {
        const int sign = lr & 1;
#pragma unroll
        for (int mi = 0; mi < 2; ++mi) {
            const int s  = bm*16 + mi*8 + (lr >> 1);
            const int b  = s / NSP, r = s - b*NSP;
            const int ho = r / WO,  wo = r - WO*(r/WO);
            const int pix = b*1024 + ho*32 + wo;
            offA[mi] = (unsigned)(pix*256 + sign*128 + lg*16);
        }
    }

    const char* pa = (const char*)pixm;
    const char* pb = (const char*)bt;

    f32x4 acc[2][2] = {};

#pragma unroll
    for (int s2 = 0; s2 < 9; ++s2) {
        const int step  = s2*2 + kq;           // this wave's 9 steps
        const int khkw  = step >> 1;
        const int kh    = khkw / 3, kw = khkw - 3*(khkw/3);
        const int khalf = step & 1;
        const unsigned immA = (unsigned)(kh*8192 + kw*256 + khalf*64);

        s16x8 a0 = *(const s16x8*)(pa + (offA[0] + immA));   // L2-hot, 16 lines
        s16x8 a1 = *(const s16x8*)(pa + (offA[1] + immA));
        s16x8 b0 = *(const s16x8*)(pb + (((ng0+0)*18 + step)*64 + l)*16);  // lane-linear
        s16x8 b1 = *(const s16x8*)(pb + (((ng0+1)*18 + step)*64 + l)*16);

        acc[0][0] = __builtin_amdgcn_mfma_f32_16x16x32_bf16(a0, b0, acc[0][0], 0, 0, 0);
        acc[0][1] = __builtin_amdgcn_mfma_f32_16x16x32_bf16(a0, b1, acc[0][1], 0, 0, 0);
        acc[1][0] = __builtin_amdgcn_mfma_f32_16x16x32_bf16(a1, b0, acc[1][0], 0, 0, 0);
        acc[1][1] = __builtin_amdgcn_mfma_f32_16x16x32_bf16(a1, b1, acc[1][1], 0, 0, 0);
    }

    // ---- K-combine: kq1 -> cmb[nsub] (r-major, 2-way free), kq0 adds
    if (kq == 1) {
#pragma unroll
        for (int mi = 0; mi < 2; ++mi)
#pragma unroll
            for (int ni = 0; ni < 2; ++ni)
#pragma unroll
                for (int r = 0; r < 4; ++r)
                    cmb[nsub][((mi*2 + ni)*4 + r)*64 + l] = acc[mi][ni][r];
    }
    __syncthreads();
    if (kq == 0) {
#pragma unroll
        for (int mi = 0; mi < 2; ++mi)
#pragma unroll
            for (int ni = 0; ni < 2; ++ni)
#pragma unroll
                for (int r = 0; r < 4; ++r)
                    acc[mi][ni][r] += cmb[nsub][((mi*2 + ni)*4 + r)*64 + l];

        // epilogue write: rows mi*16 + lg*4 + r, cols ni*16 + lr (pitch 34)
        const int wrbase = lg*4*34 + lr;
#pragma unroll
        for (int mi = 0; mi < 2; ++mi)
#pragma unroll
            for (int ni = 0; ni < 2; ++ni)
#pragma unroll
                for (int r = 0; r < 4; ++r)
                    epi[nsub][wrbase + (mi*16 + r)*34 + ni*16] = acc[mi][ni][r];
    }
    __syncthreads();

    // ---- final transform + store: kq0 waves, one per nsub (32 cols = 8 o)
    if (kq == 0) {
        const float* E = &epi[nsub][0];
        const int sl = lr;
        const int s  = bm*16 + sl;
        const int b  = s / NSP;
        const int r900 = s - b*NSP;
#pragma unroll
        for (int oi = 0; oi < 2; ++oi) {
            int ol = lg*2 + oi;                    // local o 0..7
            int o  = nh*32 + nsub*8 + ol;
            float4 v0 = *(const float4*)&E[(2*sl + 0)*34 + ol*4];  // pos: d1,n1,d2,n2
            float4 v1 = *(const float4*)&E[(2*sl + 1)*34 + ol*4];  // neg
            float d1p = S.x + v0.x, n1p = S.y + v0.y;
            float d2p = S.x + v0.z, n2p = S.y + v0.w;
            float d1n = S.z + v1.x, n1n = S.w + v1.y;
            float d2n = S.z + v1.z, n2n = S.w + v1.w;
            float P = __expf(n1p/d1p) - __expf(n2p/d2p)
                    - __expf(n1n/d1n) + __expf(n2n/d2n);
            out[((size_t)(b*OO + o))*NSP + r900] = P + bias[o];
        }
    }
}

extern "C" void kernel_launch(void* const* d_in, const int* in_sizes, int n_in,
                              void* d_out, int out_size, void* d_ws, size_t ws_size,
                              hipStream_t stream) {
    const float* x    = (const float*)d_in[0];
    const float* k1   = (const float*)d_in[1];
    const float* k2   = (const float*)d_in[2];
    const float* bias = (const float*)d_in[3];

    char* ws = (char*)d_ws;
    float4*         pixs = (float4*)(ws);                    // 64 KB
    unsigned*       pixm = (unsigned*)(ws + 0x10000);        // 1 MB
    unsigned short* bt   = (unsigned short*)(ws + 0x110000); // 294,912 B
    float*          out  = (float*)d_out;

    hipLaunchKernelGGL(smorph_prep, dim3((T1 + TB + 255)/256), dim3(256), 0, stream,
                       x, k1, k2, pixs, pixm, bt);
    hipLaunchKernelGGL(smorph_gemm, dim3(450), dim3(512), 0, stream,
                       pixm, bt, pixs, bias, out);
}

// Round 19
// 20.601 us; speedup vs baseline: 1.1435x; 1.1435x over previous
//
#include <hip/hip_runtime.h>
#include <math.h>

// BipolarMorphological2D SMorph as a bf16 MFMA GEMM (R19).
// delta-form: e^kf = 1 + delta -> d = S_m + GEMM(m,delta); n = S_mlm + GEMM(..)
//   M = 7200 (s*2+sign), N = 256 (o*4+tbl), K = 576 (c*2+{m,mlm} per 3x3 pos)
// R19 vs R17: K-split 4 (R15's proven no-duplication lever, applied again).
// Block = 8 waves (kq4 x nhf2); wave = 32M x 64N x 4-5 steps (kq<2 take the
// 2 extra). Total loads unchanged (97K), per-wave serial chain halved (~27
// loads), 3600 waves = 3.5 waves/SIMD. 2-round LDS combine tree (3 barriers).
// R18's mistake (N-split -> 4x A-load duplication) avoided.

typedef float  f32x4 __attribute__((ext_vector_type(4)));
typedef short  s16x8 __attribute__((ext_vector_type(8)));

#define BB   4
#define CC   32
#define HH   32
#define WW   32
#define OO   64
#define HO   30
#define WO   30
#define NSP  900
#define KDIM 576

#define T1   131072            // branch1: pixel sums + pixm pack
#define TB   18432             // branch2: B pack

__device__ __forceinline__ unsigned short f2bf(float f) {
    unsigned u = __float_as_uint(f);
    return (unsigned short)((u + 0x7FFFu + ((u >> 16) & 1u)) >> 16);
}

// ---- prep: pixs[pix] = fp32 c-sums (Smp, Smlmp, Smn, Smlmn)
//            pixm[pix*64 + sign*32 + c] = packed bf16 (m | mlm<<16)
//            bt: bf16 B in MFMA-frag order: [ng(16)][step(18)][lane(64)] x 16B
__global__ __launch_bounds__(256) void smorph_prep(
    const float* __restrict__ x, const float* __restrict__ k1,
    const float* __restrict__ k2, float4* __restrict__ pixs,
    unsigned* __restrict__ pixm, unsigned short* __restrict__ bt)
{
    const int t = blockIdx.x * 256 + threadIdx.x;

    if (t < T1) {
        const int pix = t >> 5, c = t & 31;
        const int b = pix >> 10, h = (pix >> 5) & 31, w = pix & 31;
        float v = x[b*32768 + c*1024 + h*32 + w];
        float mp = fmaxf(v, 0.1f), mn = fmaxf(-v, 0.1f);
        float lp = mp * logf(mp), ln_ = mn * logf(mn);
        pixm[pix*64      + c] = (unsigned)f2bf(mp) | ((unsigned)f2bf(lp)  << 16);
        pixm[pix*64 + 32 + c] = (unsigned)f2bf(mn) | ((unsigned)f2bf(ln_) << 16);
        float s0 = mp, s1 = lp, s2 = mn, s3 = ln_;
#pragma unroll
        for (int m = 16; m >= 1; m >>= 1) {
            s0 += __shfl_xor(s0, m); s1 += __shfl_xor(s1, m);
            s2 += __shfl_xor(s2, m); s3 += __shfl_xor(s3, m);
        }
        if (c == 0) pixs[pix] = make_float4(s0, s1, s2, s3);
    } else if (t < T1 + TB) {
        const int u3 = t - T1;
        const int o = u3 & 63, p = u3 >> 6;
        const float a = k1[u3], b2 = k2[u3];
        const float d1 = expm1f(a),  q1 = a  * expf(a);
        const float d2 = expm1f(b2), q2 = b2 * expf(b2);
        const float vals[4][2] = {{d1, 0.f}, {q1, d1}, {d2, 0.f}, {q2, d2}};
#pragma unroll
        for (int tbl = 0; tbl < 4; ++tbl) {
            const int n = o*4 + tbl;
#pragma unroll
            for (int ks = 0; ks < 2; ++ks) {
                const int k    = 2*p + ks;
                const int st   = k >> 5, k32 = k & 31;
                const int lane = (n & 15) + ((k32 >> 3) << 4);
                bt[((n >> 4)*18 + st)*512 + lane*8 + (k32 & 7)] = f2bf(vals[tbl][ks]);
            }
        }
    }
}

// ---- GEMM: 450 blocks (225 bm x 2 nh) x 512 thr (8 waves: kq4 x nhf2).
// Wave: 32M x 64N x (4 or 5) steps; K-split-4 combined via 2-round LDS tree.
__global__ __launch_bounds__(512, 2) void smorph_gemm(
    const unsigned* __restrict__ pixm, const unsigned short* __restrict__ bt,
    const float4* __restrict__ pixs, const float* __restrict__ bias,
    float* __restrict__ out)
{
    __shared__ float cmb[4][2048];               // 32 KB: K-combine slots
    __shared__ __align__(16) float epi[2][32*66];// 16.9 KB: epilogue transpose

    const int tid = threadIdx.x;
    const int l   = tid & 63;
    const int w   = tid >> 6;                  // wave 0..7
    const int kq  = w >> 1;                    // K-quarter 0..3
    const int nhf = w & 1;                     // N-half within block
    const int bm  = blockIdx.x >> 1;           // M-tile (16 s, 32 rows)
    const int nh  = blockIdx.x & 1;
    const int N0  = nh*128 + nhf*64;
    const int ng0 = N0 >> 4;

    const int lr = l & 15;
    const int lg = l >> 4;

    // ---- per-lane fp32 window sums (epilogue only)
    float4 S;
    {
        const int s  = bm*16 + lr;
        const int b  = s / NSP, r = s - b*NSP;
        const int ho = r / WO,  wo = r - WO*(r/WO);
        const float4* P = pixs + (b*1024 + ho*32 + wo);
        float4 a = make_float4(0,0,0,0);
#pragma unroll
        for (int kh = 0; kh < 3; ++kh)
#pragma unroll
            for (int kw = 0; kw < 3; ++kw) {
                float4 v = P[kh*32 + kw];
                a.x += v.x; a.y += v.y; a.z += v.z; a.w += v.w;
            }
        S = a;
    }

    // A lane byte-offsets into pixm: pix*256 + sign*128 + lg*16
    unsigned offA[2];
    {
        const int sign = lr & 1;
#pragma unroll
        for (int mi = 0; mi < 2; ++mi) {
            const int s  = bm*16 + mi*8 + (lr >> 1);
            const int b  = s / NSP, r = s - b*NSP;
            const int ho = r / WO,  wo = r - WO*(r/WO);
            const int pix = b*1024 + ho*32 + wo;
            offA[mi] = (unsigned)(pix*256 + sign*128 + lg*16);
        }
    }

    const char* pa = (const char*)pixm;
    const char* pb = (const char*)bt;

    f32x4 acc[2][4] = {};

#define DO_STEP(stepv)                                                          \
    {                                                                           \
        const int step_ = (stepv);                                              \
        const int khkw_ = step_ >> 1;                                           \
        const int kh_   = khkw_ / 3, kw_ = khkw_ - 3*(khkw_/3);                 \
        const unsigned immA_ = (unsigned)(kh_*8192 + kw_*256 + (step_ & 1)*64); \
        s16x8 a0 = *(const s16x8*)(pa + (offA[0] + immA_));                     \
        s16x8 a1 = *(const s16x8*)(pa + (offA[1] + immA_));                     \
        s16x8 b0 = *(const s16x8*)(pb + (((ng0+0)*18 + step_)*64 + l)*16);      \
        s16x8 b1 = *(const s16x8*)(pb + (((ng0+1)*18 + step_)*64 + l)*16);      \
        s16x8 b2 = *(const s16x8*)(pb + (((ng0+2)*18 + step_)*64 + l)*16);      \
        s16x8 b3 = *(const s16x8*)(pb + (((ng0+3)*18 + step_)*64 + l)*16);      \
        acc[0][0] = __builtin_amdgcn_mfma_f32_16x16x32_bf16(a0, b0, acc[0][0], 0, 0, 0); \
        acc[0][1] = __builtin_amdgcn_mfma_f32_16x16x32_bf16(a0, b1, acc[0][1], 0, 0, 0); \
        acc[0][2] = __builtin_amdgcn_mfma_f32_16x16x32_bf16(a0, b2, acc[0][2], 0, 0, 0); \
        acc[0][3] = __builtin_amdgcn_mfma_f32_16x16x32_bf16(a0, b3, acc[0][3], 0, 0, 0); \
        acc[1][0] = __builtin_amdgcn_mfma_f32_16x16x32_bf16(a1, b0, acc[1][0], 0, 0, 0); \
        acc[1][1] = __builtin_amdgcn_mfma_f32_16x16x32_bf16(a1, b1, acc[1][1], 0, 0, 0); \
        acc[1][2] = __builtin_amdgcn_mfma_f32_16x16x32_bf16(a1, b2, acc[1][2], 0, 0, 0); \
        acc[1][3] = __builtin_amdgcn_mfma_f32_16x16x32_bf16(a1, b3, acc[1][3], 0, 0, 0); \
    }

#pragma unroll
    for (int s2 = 0; s2 < 4; ++s2) DO_STEP(s2*4 + kq);
    if (kq < 2) DO_STEP(16 + kq);          // wave-uniform branch, 2 extra steps
#undef DO_STEP

    // ---- K-combine round 1: kq2 -> slot(0,nhf), kq3 -> slot(1,nhf)
    if (kq >= 2) {
        float* dst = &cmb[(kq - 2)*2 + nhf][l];
#pragma unroll
        for (int mi = 0; mi < 2; ++mi)
#pragma unroll
            for (int ni = 0; ni < 4; ++ni)
#pragma unroll
                for (int r = 0; r < 4; ++r)
                    dst[((mi*4 + ni)*4 + r)*64] = acc[mi][ni][r];
    }
    __syncthreads();
    if (kq < 2) {
        const float* srcp = &cmb[kq*2 + nhf][l];
#pragma unroll
        for (int mi = 0; mi < 2; ++mi)
#pragma unroll
            for (int ni = 0; ni < 4; ++ni)
#pragma unroll
                for (int r = 0; r < 4; ++r)
                    acc[mi][ni][r] += srcp[((mi*4 + ni)*4 + r)*64];
    }
    __syncthreads();
    // ---- round 2: kq1 -> slot(0,nhf); kq0 adds + epilogue write
    if (kq == 1) {
        float* dst = &cmb[nhf][l];
#pragma unroll
        for (int mi = 0; mi < 2; ++mi)
#pragma unroll
            for (int ni = 0; ni < 4; ++ni)
#pragma unroll
                for (int r = 0; r < 4; ++r)
                    dst[((mi*4 + ni)*4 + r)*64] = acc[mi][ni][r];
    }
    __syncthreads();
    if (kq == 0) {
        const float* srcp = &cmb[nhf][l];
#pragma unroll
        for (int mi = 0; mi < 2; ++mi)
#pragma unroll
            for (int ni = 0; ni < 4; ++ni)
#pragma unroll
                for (int r = 0; r < 4; ++r)
                    acc[mi][ni][r] += srcp[((mi*4 + ni)*4 + r)*64];

        // epilogue write: acc -> epi[nhf] [row 0..31][col 0..63], pitch 66
        const int wrbase = lg*4*66 + lr;
#pragma unroll
        for (int mi = 0; mi < 2; ++mi)
#pragma unroll
            for (int ni = 0; ni < 4; ++ni)
#pragma unroll
                for (int r = 0; r < 4; ++r)
                    epi[nhf][wrbase + (mi*16 + r)*66 + ni*16] = acc[mi][ni][r];
    }
    __syncthreads();

    if (kq == 0) {
        const int sl = lr;
        const int s  = bm*16 + sl;
        const int b  = s / NSP;
        const int r900 = s - b*NSP;
#pragma unroll
        for (int oi = 0; oi < 4; ++oi) {
            int ol = lg*4 + oi;
            int o  = (N0 >> 2) + ol;
            float4 v0 = *(const float4*)&epi[nhf][(2*sl + 0)*66 + ol*4];  // pos
            float4 v1 = *(const float4*)&epi[nhf][(2*sl + 1)*66 + ol*4];  // neg
            float d1p = S.x + v0.x, n1p = S.y + v0.y;
            float d2p = S.x + v0.z, n2p = S.y + v0.w;
            float d1n = S.z + v1.x, n1n = S.w + v1.y;
            float d2n = S.z + v1.z, n2n = S.w + v1.w;
            float P = __expf(n1p/d1p) - __expf(n2p/d2p)
                    - __expf(n1n/d1n) + __expf(n2n/d2n);
            out[((size_t)(b*OO + o))*NSP + r900] = P + bias[o];
        }
    }
}

extern "C" void kernel_launch(void* const* d_in, const int* in_sizes, int n_in,
                              void* d_out, int out_size, void* d_ws, size_t ws_size,
                              hipStream_t stream) {
    const float* x    = (const float*)d_in[0];
    const float* k1   = (const float*)d_in[1];
    const float* k2   = (const float*)d_in[2];
    const float* bias = (const float*)d_in[3];

    char* ws = (char*)d_ws;
    float4*         pixs = (float4*)(ws);                    // 64 KB
    unsigned*       pixm = (unsigned*)(ws + 0x10000);        // 1 MB
    unsigned short* bt   = (unsigned short*)(ws + 0x110000); // 294,912 B
    float*          out  = (float*)d_out;

    hipLaunchKernelGGL(smorph_prep, dim3((T1 + TB + 255)/256), dim3(256), 0, stream,
                       x, k1, k2, pixs, pixm, bt);
    hipLaunchKernelGGL(smorph_gemm, dim3(450), dim3(512), 0, stream,
                       pixm, bt, pixs, bias, out);
}